// Round 9
// baseline (69.381 us; speedup 1.0000x reference)
//
#include <hip/hip_runtime.h>

#define CH    512
#define BATCH 16
#define QB    4        // batch planes per absmax block / per gather block
#define NQ    (BATCH / QB)   // 4 partials per channel = one f4
#define HW    3136     // 56*56
#define HW4   784      // HW/4 (float4 per image plane)
#define THRESH 8.0f

typedef float f4 __attribute__((ext_vector_type(4)));

// ---- Kernel 1: partial[c*NQ+q] = max|x[b in q*QB.., c, :, :]| -----------
// linear block id = c + 512*q -> XCD = c % 8 (512 = 0 mod 8)
__global__ __launch_bounds__(256) void absmax_kernel(const float* __restrict__ x,
                                                     float* __restrict__ partial) {
    const int c   = blockIdx.x;
    const int q   = blockIdx.y;
    const int tid = threadIdx.x;
    float m = 0.0f;
    for (int bb = 0; bb < QB; ++bb) {
        const int b = q * QB + bb;
        const f4* src = reinterpret_cast<const f4*>(x) + (size_t)(b * CH + c) * HW4;
        for (int p = tid; p < HW4; p += 256) {
            f4 v = src[p];
            m = fmaxf(m, fmaxf(fmaxf(fabsf(v.x), fabsf(v.y)),
                               fmaxf(fabsf(v.z), fabsf(v.w))));
        }
    }
    __shared__ float sm[256];
    sm[tid] = m;
    __syncthreads();
    for (int off = 128; off > 0; off >>= 1) {
        if (tid < off) sm[tid] = fmaxf(sm[tid], sm[tid + off]);
        __syncthreads();
    }
    if (tid == 0) partial[c * NQ + q] = sm[0];
}

// ---- Kernel 2: channel-major gather. block w -> (c = w&511, bq = w>>9) --
// XCD(w) = w%8 = c%8 == absmax's XCD for channel c -> L2-local reads.
// Each element read ONCE, NT-stored T times (register replication).
__global__ __launch_bounds__(256) void gather_kernel(const float* __restrict__ x,
                                                     const float* __restrict__ partial,
                                                     float* __restrict__ out,
                                                     float* __restrict__ out_tail,
                                                     int R) {
    const int w  = blockIdx.x;     // 0..2047
    const int c  = w & (CH - 1);   // source channel
    const int bq = w >> 9;         // batch quad

    const int tid  = threadIdx.x;
    const int lane = tid & 63;
    const int wv   = tid >> 6;     // wave id (4 waves)

    // --- plan (once per block): thread t owns channels c0=2t, c1=2t+1 ----
    const int c0 = tid * 2, c1 = c0 + 1;
    f4 p0 = reinterpret_cast<const f4*>(partial)[c0];   // channel c0's 4 partials
    f4 p1 = reinterpret_cast<const f4*>(partial)[c1];
    float m0 = fmaxf(fmaxf(p0.x, p0.y), fmaxf(p0.z, p0.w));
    float m1 = fmaxf(fmaxf(p1.x, p1.y), fmaxf(p1.z, p1.w));
    int T0 = (m0 > THRESH) ? (int)ceilf(m0 * 0.125f) : 0;  // ceil(m/8), exact
    int T1 = (m1 > THRESH) ? (int)ceilf(m1 * 0.125f) : 0;
    const int v = T0 + T1;

    int s = v;                    // wave-inclusive scan (no barriers)
    #pragma unroll
    for (int off = 1; off < 64; off <<= 1) {
        int t2 = __shfl_up(s, off, 64);
        if (lane >= off) s += t2;
    }
    __shared__ int wsum[4];
    if (lane == 63) wsum[wv] = s;
    __syncthreads();
    int woff = 0;
    #pragma unroll
    for (int k = 0; k < 4; ++k) if (k < wv) woff += wsum[k];
    const int start0 = woff + s - v;       // first output slot of channel c0
    const int start1 = start0 + T0;

    // publish per-channel (start, T) to LDS so the block can look up its c
    __shared__ short sStart[CH];
    __shared__ char  sT[CH];
    sStart[c0] = (short)start0;  sT[c0] = (char)T0;
    sStart[c1] = (short)start1;  sT[c1] = (char)T1;

    // block 0 writes the outlier-id tail (fp32 channel ids, channel order)
    if (w == 0) {
        const int o0 = (T0 > 0), o1 = (T1 > 0);
        const int v2 = o0 + o1;
        int s2 = v2;
        #pragma unroll
        for (int off = 1; off < 64; off <<= 1) {
            int t2 = __shfl_up(s2, off, 64);
            if (lane >= off) s2 += t2;
        }
        __shared__ int wsum2[4];
        if (lane == 63) wsum2[wv] = s2;
        __syncthreads();
        int woff2 = 0;
        #pragma unroll
        for (int k = 0; k < 4; ++k) if (k < wv) woff2 += wsum2[k];
        const int ex2 = woff2 + s2 - v2;
        if (o0) out_tail[ex2]      = (float)c0;
        if (o1) out_tail[ex2 + o0] = (float)c1;
    }
    __syncthreads();

    const int T     = sT[c];
    const int start = sStart[c];
    if (T == 0) return;                              // channel not an outlier
    const float scale = (float)(1.0 / (double)T);    // numpy f64->f32 rounding

    for (int bb = 0; bb < QB; ++bb) {
        const int b = bq * QB + bb;
        const f4* src  = reinterpret_cast<const f4*>(x)
                         + (size_t)(b * CH + c) * HW4;
        f4*       dst0 = reinterpret_cast<f4*>(out)
                         + ((size_t)b * R + start) * HW4;   // T contiguous planes
        for (int p = tid; p < HW4; p += 256) {
            f4 vv = src[p];                                 // read ONCE
            vv.x *= scale; vv.y *= scale; vv.z *= scale; vv.w *= scale;
            for (int k = 0; k < T; ++k)                     // write T replicas
                __builtin_nontemporal_store(vv, &dst0[(size_t)k * HW4 + p]);
        }
    }
}

extern "C" void kernel_launch(void* const* d_in, const int* in_sizes, int n_in,
                              void* d_out, int out_size, void* d_ws, size_t ws_size,
                              hipStream_t stream) {
    const float* x = (const float*)d_in[0];
    float* out = (float*)d_out;

    // out_size = 50176*R + n_out,  n_out <= 512 < 50176  -> unique split
    const int plane = BATCH * HW;               // 50176
    const int R     = out_size / plane;         // total replicated channels

    float* partial = (float*)d_ws;              // CH*NQ floats (8 KB)

    absmax_kernel<<<dim3(CH, NQ), 256, 0, stream>>>(x, partial);
    if (R > 0) {
        gather_kernel<<<dim3(CH * NQ), 256, 0, stream>>>(
            x, partial, out, out + (size_t)R * plane, R);
    }
}